// Round 3
// baseline (1514.057 us; speedup 1.0000x reference)
//
#include <hip/hip_runtime.h>
#include <math.h>

#define BATCH 262144
#define NUM_CLASSES 1000
#define NF4 250   // float4 chunks per row (1000/4)
// ALPHA=1.0, GAMMA=2.0, K=0.5, T=3.0 baked in below.
//
// MEASUREMENT ROUND: launch an identical dummy copy of dbfl_main (results
// into unused ws doubles acc[2..3], discarded) before the real one.
//   main_2048 = dur_us(this round) - 1313.5
// This measures dbfl_main's exact duration via the bench clock, settling
// whether the 1313 us total is {fill+main~650}, {fill+restore+main~340},
// or {fixed~1140 + main~170 (roofline)}.

__global__ __launch_bounds__(256, 4) void dbfl_main(
    const float* __restrict__ output,   // [BATCH, NUM_CLASSES]
    const int* __restrict__ target,     // [BATCH]
    const float* __restrict__ wt,       // [NUM_CLASSES, NUM_CLASSES]
    double* __restrict__ acc)           // acc[0]=loss1, acc[1]=loss2
{
    const int lane = threadIdx.x & 63;
    const int wib  = threadIdx.x >> 6;                       // wave in block
    const int wpb  = blockDim.x >> 6;                        // waves per block
    const long long gwave  = (long long)blockIdx.x * wpb + wib;
    const long long nwaves = (long long)gridDim.x * wpb;

    float acc1 = 0.f, acc2 = 0.f;

    long long row = gwave;
    if (row < BATCH) {
        // ---- prologue: load first row into vc ----
        const float4* rp4 = (const float4*)(output + row * (long long)NUM_CLASSES);
        float4 vc[4];
#pragma unroll
        for (int c = 0; c < 4; ++c) {
            const int f = lane + 64 * c;
            vc[c] = (f < NF4) ? rp4[f]
                              : make_float4(-INFINITY, -INFINITY, -INFINITY, -INFINITY);
        }
        int tcur = target[row];

        for (;;) {
            // ---- issue next row's loads FIRST (latency hides under compute) ----
            const long long nrow = row + nwaves;
            const bool have_next = (nrow < BATCH);           // wave-uniform
            float4 vn[4];
            int tnext = 0;
            if (have_next) {
                const float4* np4 = (const float4*)(output + nrow * (long long)NUM_CLASSES);
#pragma unroll
                for (int c = 0; c < 4; ++c) {
                    const int f = lane + 64 * c;
                    vn[c] = (f < NF4) ? np4[f]
                                      : make_float4(-INFINITY, -INFINITY, -INFINITY, -INFINITY);
                }
                tnext = target[nrow];
            }

            // ---- wave max (pure max reduce; order-independent, exact) ----
            float bm = -INFINITY;
#pragma unroll
            for (int c = 0; c < 4; ++c)
                bm = fmaxf(bm, fmaxf(fmaxf(vc[c].x, vc[c].y), fmaxf(vc[c].z, vc[c].w)));
            float wm = bm;
#pragma unroll
            for (int off = 32; off > 0; off >>= 1)
                wm = fmaxf(wm, __shfl_xor(wm, off, 64));

            // ---- argmax col: min col where value == wm (first occurrence) ----
            int bi = 0x7fffffff;
#pragma unroll
            for (int c = 3; c >= 0; --c) {
                const int base = (lane + 64 * c) * 4;
                if (vc[c].w == wm) bi = base + 3;
                if (vc[c].z == wm) bi = base + 2;
                if (vc[c].y == wm) bi = base + 1;
                if (vc[c].x == wm) bi = base + 0;
            }
            int wi = bi;
#pragma unroll
            for (int off = 32; off > 0; off >>= 1)
                wi = min(wi, __shfl_xor(wi, off, 64));

            // ---- hoisted wt lookup (L2 latency overlaps the exp-sum below) ----
            const int t_s  = __builtin_amdgcn_readfirstlane(tcur);
            const int wi_s = __builtin_amdgcn_readfirstlane(wi);
            const float w = wt[(long long)t_s * NUM_CLASSES + wi_s];

            // ---- sum of exp(x - wm): same order as verified baseline ----
            float s = 0.f;
#pragma unroll
            for (int c = 0; c < 4; ++c) {
                s += __expf(vc[c].x - wm);
                s += __expf(vc[c].y - wm);
                s += __expf(vc[c].z - wm);
                s += __expf(vc[c].w - wm);
            }
#pragma unroll
            for (int off = 32; off > 0; off >>= 1)
                s += __shfl_xor(s, off, 64);

            // ---- x_t from registers (bit-identical to the memory reload) ----
            const int f4  = t_s >> 2;                        // owning float4 index
            const int src = f4 & 63;                         // owning lane
            const int ch  = f4 >> 6;                         // chunk (uniform)
            const int cm  = t_s & 3;                         // component (uniform)
            float4 vsel = vc[0];
            if (ch == 1) vsel = vc[1];
            else if (ch == 2) vsel = vc[2];
            else if (ch == 3) vsel = vc[3];
            float cand = vsel.x;
            if (cm == 1) cand = vsel.y;
            else if (cm == 2) cand = vsel.z;
            else if (cm == 3) cand = vsel.w;
            const float xt = __shfl(cand, src, 64);

            const float ce = wm + __logf(s) - xt;            // lse - x_t
            const float pt = __expf(-ce);
            const float om_pt = 1.f - pt;
            const float fl = om_pt * om_pt * ce;             // alpha=1, gamma=2
            if (lane == 0) {
                if (w != 0.f) acc1 += fl * w;                // mask <=> weight nonzero
                else          acc2 += fl;
            }

            if (!have_next) break;
#pragma unroll
            for (int c = 0; c < 4; ++c) vc[c] = vn[c];       // rotate buffers
            tcur = tnext;
            row  = nrow;
        }
    }

    __shared__ float sh1[8], sh2[8];
    if (lane == 0) { sh1[wib] = acc1; sh2[wib] = acc2; }
    __syncthreads();
    if (threadIdx.x == 0) {
        float a = 0.f, b = 0.f;
        for (int i = 0; i < wpb; ++i) { a += sh1[i]; b += sh2[i]; }
        unsafeAtomicAdd(&acc[0], (double)a);                  // HW global_atomic_add_f64
        unsafeAtomicAdd(&acc[1], (double)b);
    }
}

__global__ void dbfl_final(const double* __restrict__ acc, float* __restrict__ out)
{
    const double loss1 = acc[0];
    const double loss2 = acc[1];
    const double b  = (double)BATCH;
    const double l1 = loss1 / b;
    const double l2 = loss2 / b;
    const double w2 = 1.0 / (1.0 + exp(-0.5 * (l1 - 3.0)));   // sigmoid(K*(l1-T))
    const double total = (loss1 > 0.0) ? (l1 + w2 * l2) : l2;
    out[0] = (float)total;
}

extern "C" void kernel_launch(void* const* d_in, const int* in_sizes, int n_in,
                              void* d_out, int out_size, void* d_ws, size_t ws_size,
                              hipStream_t stream)
{
    const float* output = (const float*)d_in[0];
    const int*   target = (const int*)d_in[1];
    const float* wt     = (const float*)d_in[2];
    // d_in[3] (in_dict bool mask) intentionally unused: mask <=> wt != 0.

    double* acc = (double*)d_ws;                    // [0..1] real, [2..3] dummy sink
    hipMemsetAsync(d_ws, 0, 4 * sizeof(double), stream);      // ws is poisoned 0xAA

    const int block = 256;                                     // 4 waves/block
    const int grid  = 2048;                                    // 8192 waves, 32 rows each

    // TIMER DUMMY: identical launch, results discarded (acc[2..3]).
    // main_2048 = dur_us - 1313.5.
    dbfl_main<<<grid, block, 0, stream>>>(output, target, wt, acc + 2);
    // Real pass (unchanged semantics).
    dbfl_main<<<grid, block, 0, stream>>>(output, target, wt, acc);
    dbfl_final<<<1, 1, 0, stream>>>(acc, (float*)d_out);
}

// Round 4
// 1293.803 us; speedup vs baseline: 1.1702x; 1.1702x over previous
//
#include <hip/hip_runtime.h>
#include <math.h>

#define BATCH 262144
#define NUM_CLASSES 1000
#define NF4 250   // float4 chunks per row (1000/4)
// ALPHA=1.0, GAMMA=2.0, K=0.5, T=3.0 baked in below.
//
// Round 4: main measured at 200.6 us (5.25 TB/s) vs 6.3 TB/s achievable.
// Attack the last 17%: nontemporal (nt) loads on the never-reused 1.05 GB
// row stream + lean non-pipelined body (pipelining proven neutral in R1)
// + launch_bounds(256,6) and grid 4096 for more waves in flight.

typedef float f32x4 __attribute__((ext_vector_type(4)));

__global__ __launch_bounds__(256, 6) void dbfl_main(
    const float* __restrict__ output,   // [BATCH, NUM_CLASSES]
    const int* __restrict__ target,     // [BATCH]
    const float* __restrict__ wt,       // [NUM_CLASSES, NUM_CLASSES]
    double* __restrict__ acc)           // acc[0]=loss1, acc[1]=loss2
{
    const int lane = threadIdx.x & 63;
    const int wib  = threadIdx.x >> 6;                       // wave in block
    const int wpb  = blockDim.x >> 6;                        // waves per block
    const long long gwave  = (long long)blockIdx.x * wpb + wib;
    const long long nwaves = (long long)gridDim.x * wpb;

    float acc1 = 0.f, acc2 = 0.f;
    const f32x4 vpad = {-INFINITY, -INFINITY, -INFINITY, -INFINITY};

    for (long long row = gwave; row < BATCH; row += nwaves) {
        const f32x4* rp4 = (const f32x4*)(output + row * (long long)NUM_CLASSES);
        const int tcur = target[row];

        // ---- streaming (nontemporal) row load: 4 x dwordx4 nt per lane ----
        f32x4 vc[4];
#pragma unroll
        for (int c = 0; c < 4; ++c) {
            const int f = lane + 64 * c;
            vc[c] = (f < NF4) ? __builtin_nontemporal_load(rp4 + f) : vpad;
        }

        // ---- wave max (pure max reduce; order-independent, exact) ----
        float bm = -INFINITY;
#pragma unroll
        for (int c = 0; c < 4; ++c)
            bm = fmaxf(bm, fmaxf(fmaxf(vc[c].x, vc[c].y), fmaxf(vc[c].z, vc[c].w)));
        float wm = bm;
#pragma unroll
        for (int off = 32; off > 0; off >>= 1)
            wm = fmaxf(wm, __shfl_xor(wm, off, 64));

        // ---- argmax col: min col where value == wm (first occurrence) ----
        // descending scan so the smallest matching col wins per lane;
        // -inf pad lanes can never equal the finite wm.
        int bi = 0x7fffffff;
#pragma unroll
        for (int c = 3; c >= 0; --c) {
            const int base = (lane + 64 * c) * 4;
            if (vc[c].w == wm) bi = base + 3;
            if (vc[c].z == wm) bi = base + 2;
            if (vc[c].y == wm) bi = base + 1;
            if (vc[c].x == wm) bi = base + 0;
        }
        int wi = bi;
#pragma unroll
        for (int off = 32; off > 0; off >>= 1)
            wi = min(wi, __shfl_xor(wi, off, 64));

        // ---- hoisted wt lookup (L2 latency overlaps the exp-sum below) ----
        const int t_s  = __builtin_amdgcn_readfirstlane(tcur);
        const int wi_s = __builtin_amdgcn_readfirstlane(wi);
        const float w = wt[(long long)t_s * NUM_CLASSES + wi_s];   // cached (no nt)

        // ---- sum of exp(x - wm): same order as verified baseline ----
        float s = 0.f;
#pragma unroll
        for (int c = 0; c < 4; ++c) {
            s += __expf(vc[c].x - wm);
            s += __expf(vc[c].y - wm);
            s += __expf(vc[c].z - wm);
            s += __expf(vc[c].w - wm);
        }
#pragma unroll
        for (int off = 32; off > 0; off >>= 1)
            s += __shfl_xor(s, off, 64);

        // ---- x_t from registers (bit-identical to the memory reload) ----
        const int f4  = t_s >> 2;                        // owning float4 index
        const int src = f4 & 63;                         // owning lane
        const int ch  = f4 >> 6;                         // chunk (uniform)
        const int cm  = t_s & 3;                         // component (uniform)
        f32x4 vsel = vc[0];
        if (ch == 1) vsel = vc[1];
        else if (ch == 2) vsel = vc[2];
        else if (ch == 3) vsel = vc[3];
        float cand = vsel.x;
        if (cm == 1) cand = vsel.y;
        else if (cm == 2) cand = vsel.z;
        else if (cm == 3) cand = vsel.w;
        const float xt = __shfl(cand, src, 64);

        const float ce = wm + __logf(s) - xt;            // lse - x_t
        const float pt = __expf(-ce);
        const float om_pt = 1.f - pt;
        const float fl = om_pt * om_pt * ce;             // alpha=1, gamma=2
        if (lane == 0) {
            if (w != 0.f) acc1 += fl * w;                // mask <=> weight nonzero
            else          acc2 += fl;
        }
    }

    __shared__ float sh1[8], sh2[8];
    if (lane == 0) { sh1[wib] = acc1; sh2[wib] = acc2; }
    __syncthreads();
    if (threadIdx.x == 0) {
        float a = 0.f, b = 0.f;
        for (int i = 0; i < wpb; ++i) { a += sh1[i]; b += sh2[i]; }
        unsafeAtomicAdd(&acc[0], (double)a);                  // HW global_atomic_add_f64
        unsafeAtomicAdd(&acc[1], (double)b);
    }
}

__global__ void dbfl_final(const double* __restrict__ acc, float* __restrict__ out)
{
    const double loss1 = acc[0];
    const double loss2 = acc[1];
    const double b  = (double)BATCH;
    const double l1 = loss1 / b;
    const double l2 = loss2 / b;
    const double w2 = 1.0 / (1.0 + exp(-0.5 * (l1 - 3.0)));   // sigmoid(K*(l1-T))
    const double total = (loss1 > 0.0) ? (l1 + w2 * l2) : l2;
    out[0] = (float)total;
}

extern "C" void kernel_launch(void* const* d_in, const int* in_sizes, int n_in,
                              void* d_out, int out_size, void* d_ws, size_t ws_size,
                              hipStream_t stream)
{
    const float* output = (const float*)d_in[0];
    const int*   target = (const int*)d_in[1];
    const float* wt     = (const float*)d_in[2];
    // d_in[3] (in_dict bool mask) intentionally unused: mask <=> wt != 0.

    double* acc = (double*)d_ws;
    hipMemsetAsync(d_ws, 0, 2 * sizeof(double), stream);      // ws is poisoned 0xAA

    const int block = 256;                                     // 4 waves/block
    const int grid  = 4096;                                    // 16384 waves, 16 rows each
    dbfl_main<<<grid, block, 0, stream>>>(output, target, wt, acc);
    dbfl_final<<<1, 1, 0, stream>>>(acc, (float*)d_out);
}